// Round 3
// baseline (268.154 us; speedup 1.0000x reference)
//
#include <hip/hip_runtime.h>
#include <hip/hip_bf16.h>
#include <math.h>

// Problem dims
#define BATCH 8192
#define INF   1024
#define LEAFW 256
#define OUTF  1024
#define NLEAF 16
#define NNODE 15
#define NTOT  4096      // NLEAF * LEAFW
#define KEXT  4160      // 4096 + 64 (mixture @ B2 folded into GEMM2's K)

typedef __bf16 bf16;
typedef __bf16 bf16x4 __attribute__((ext_vector_type(4)));
typedef __bf16 bf16x8 __attribute__((ext_vector_type(8)));
typedef float  f32x4  __attribute__((ext_vector_type(4)));

// ---------------------------------------------------------------------------
// Merged weight-prep + gating kernel (one launch, independent block roles):
//   blocks [0,4096):      w1s[l][f][h] fp32 -> W1T[l*256+h][f] bf16 (ld 1024)
//   blocks [4096,8192):   w2s[l][h][o] fp32 -> W2T[o][l*256+h] bf16 (ld KEXT)
//   blocks [8192,8448):   W2T cols 4096..4159 = b2s^T | 0
//   blocks [8448,10496):  gating: mixture + x->bf16 convert (4 rows/block)
__global__ __launch_bounds__(256) void prep_gating_kernel(
    const float* __restrict__ w1, const float* __restrict__ w2,
    const float* __restrict__ b2s, const float4* __restrict__ x4,
    const float4* __restrict__ nw4, const float* __restrict__ nb,
    bf16* __restrict__ W1T, bf16* __restrict__ W2T, float* __restrict__ mg,
    bf16* __restrict__ Aact, bf16x4* __restrict__ Xbf4) {
  __shared__ float tile[32][33];
  int b = blockIdx.x;
  int t = threadIdx.x;

  if (b < 8448) {  // ---- weight prep ----
    int tx = t & 31, ty = t >> 5;  // (32, 8)
    if (b < 4096) {                // w1 transpose
      int l = b >> 8, rem = b & 255;
      int hb = (rem & 7) * 32, fb = (rem >> 3) * 32;
      const float* in1 = w1 + (size_t)l * INF * LEAFW;
#pragma unroll
      for (int i = 0; i < 4; ++i)
        tile[ty + 8 * i][tx] =
            in1[(size_t)(fb + ty + 8 * i) * LEAFW + hb + tx];
      __syncthreads();
#pragma unroll
      for (int i = 0; i < 4; ++i)
        W1T[(size_t)(l * LEAFW + hb + ty + 8 * i) * INF + fb + tx] =
            (bf16)tile[tx][ty + 8 * i];
    } else if (b < 8192) {  // w2 transpose
      int bb = b - 4096;
      int l = bb >> 8, rem = bb & 255;
      int ob = (rem & 31) * 32, hb = (rem >> 5) * 32;
      const float* in2 = w2 + (size_t)l * LEAFW * OUTF;
#pragma unroll
      for (int i = 0; i < 4; ++i)
        tile[ty + 8 * i][tx] =
            in2[(size_t)(hb + ty + 8 * i) * OUTF + ob + tx];
      __syncthreads();
#pragma unroll
      for (int i = 0; i < 4; ++i)
        W2T[(size_t)(ob + ty + 8 * i) * KEXT + l * LEAFW + hb + tx] =
            (bf16)tile[tx][ty + 8 * i];
    } else {  // W2T extension columns
      int i = (b - 8192) * 256 + t;  // < 1024*64
      int o = i >> 6, j = i & 63;
      W2T[(size_t)o * KEXT + NTOT + j] =
          (j < NLEAF) ? (bf16)b2s[(size_t)j * OUTF + o] : (bf16)0.f;
    }
    return;
  }

  // ---- gating: one wave per row ----
  int row  = (b - 8448) * 4 + (t >> 6);
  int lane = t & 63;
  const float4* xr4 = x4 + (size_t)row * (INF / 4);

  float p[NNODE];
#pragma unroll
  for (int j = 0; j < NNODE; ++j) p[j] = 0.f;
#pragma unroll
  for (int c = 0; c < INF / 256; ++c) {  // 4 iters, float4 per lane
    int idx = c * 64 + lane;
    float4 xv = xr4[idx];
#pragma unroll
    for (int j = 0; j < NNODE; ++j) {
      float4 wv = nw4[j * (INF / 4) + idx];
      p[j] += xv.x * wv.x + xv.y * wv.y + xv.z * wv.z + xv.w * wv.w;
    }
    bf16x4 o = {(bf16)xv.x, (bf16)xv.y, (bf16)xv.z, (bf16)xv.w};
    Xbf4[(size_t)row * (INF / 4) + idx] = o;
  }
#pragma unroll
  for (int j = 0; j < NNODE; ++j) {
    float v = p[j];
#pragma unroll
    for (int off = 32; off > 0; off >>= 1) v += __shfl_xor(v, off);
    p[j] = 1.f / (1.f + expf(-(v + nb[j])));  // sigmoid
  }
  float mixv[NLEAF];
#pragma unroll
  for (int L = 0; L < NLEAF; ++L) {
    int n1 = 1 + (L >> 3), n2 = 3 + (L >> 2), n3 = 7 + (L >> 1);
    float m = ((L >> 3) & 1) ? p[0] : (1.f - p[0]);
    m *= ((L >> 2) & 1) ? p[n1] : (1.f - p[n1]);
    m *= ((L >> 1) & 1) ? p[n2] : (1.f - p[n2]);
    m *= (L & 1) ? p[n3] : (1.f - p[n3]);
    mixv[L] = m;
  }
  bf16* arow = Aact + (size_t)row * KEXT + NTOT;
  if (lane == 0) {
#pragma unroll
    for (int L = 0; L < NLEAF; ++L) {
      mg[row * NLEAF + L] = mixv[L];
      arow[L] = (bf16)mixv[L];
    }
  }
  if (lane >= 16) arow[lane] = (bf16)0.f;  // cols 4112..4159
}

// ---------------------------------------------------------------------------
// Shared GEMM helpers
template <int N>
__device__ __forceinline__ void wait_vmcnt() {
  asm volatile("s_waitcnt vmcnt(%0)" ::"n"(N) : "memory");
}
__device__ __forceinline__ void barrier_fence() {
  asm volatile("" ::: "memory");
  __builtin_amdgcn_s_barrier();
  asm volatile("" ::: "memory");
}

// ---------------------------------------------------------------------------
// Unified 2-phase counted-vmcnt bf16 MFMA GEMM (the structure that measured
// best in round 2 as gemm2): C[8192][N] = A[8192][K] @ BT[N][K]^T.
// 128x256 tile, 8 waves (2M x 4N), 2 phases/K-tile x 16 MFMA each.
//   P0: read A(8)+B0(4); stage (t+1).{A,B0}; 16 MFMA; vmcnt(4); barrier.
//   P1: read B1(4);      stage (t+1).B1;     16 MFMA; vmcnt(2); barrier.
// vmcnt never 0 in the loop (T4). XOR chunk swizzle applied identically on
// stage-source and ds_read (involution) -> conflict-free, linear LDS dest.
// EPI=0: outB[row][col] (ld KEXT) = relu(acc+bias[col]) * mg[row][bn>>8]
// EPI=1: outF[row][col] (ld OUTF) = acc
template <int EPI, int KLD, int NTN>
__global__ __launch_bounds__(512, 2) void gemm_kernel(
    const bf16* __restrict__ A, const bf16* __restrict__ BT,
    const float* __restrict__ bias, const float* __restrict__ mg,
    bf16* __restrict__ outB, float* __restrict__ outF) {
  constexpr int NT  = KLD / 64;   // K-tiles (16 or 65)
  constexpr int ASZ = 128 * 64;   // elems per A buf (16 KiB)
  constexpr int BSZ = 256 * 64;   // elems per B buf (32 KiB)
  __shared__ __align__(16) bf16 As[2 * ASZ];
  __shared__ __align__(16) bf16 Bs[2 * BSZ];

  const int t = threadIdx.x, lane = t & 63, w = t >> 6;
  const int wm = w >> 2, wn = w & 3;
  // XCD-bijective swizzle: nwg = 64*NTN, always % 8 == 0
  const int orig = blockIdx.x;
  const int swz  = (orig & 7) * (8 * NTN) + (orig >> 3);
  const int bm = (swz / NTN) * 128, bn = (swz % NTN) * 256;
  const int lr = t >> 3, cs = t & 7;
  const int scol = ((cs ^ (lr & 7)) << 3);  // pre-swizzled global col

  auto stageA = [&](int kt, int buf) {
#pragma unroll
    for (int q = 0; q < 2; ++q) {
      const bf16* src = A + (size_t)(bm + q * 64 + lr) * KLD + kt * 64 + scol;
      __builtin_amdgcn_global_load_lds(
          (const __attribute__((address_space(1))) void*)src,
          (__attribute__((address_space(3))) void*)((char*)As +
                                                    buf * (ASZ * 2) +
                                                    q * 8192 + t * 16),
          16, 0, 0);
    }
  };
  auto stageB = [&](int kt, int h, int buf) {
#pragma unroll
    for (int q = 0; q < 2; ++q) {
      const bf16* src =
          BT + (size_t)(bn + h * 128 + q * 64 + lr) * KLD + kt * 64 + scol;
      __builtin_amdgcn_global_load_lds(
          (const __attribute__((address_space(1))) void*)src,
          (__attribute__((address_space(3))) void*)((char*)Bs +
                                                    buf * (BSZ * 2) +
                                                    h * 16384 + q * 8192 +
                                                    t * 16),
          16, 0, 0);
    }
  };
  auto rdA = [&](int buf, int i, int kk) -> bf16x8 {
    int r  = (i >> 1) * 64 + wm * 32 + (i & 1) * 16 + (lane & 15);
    int ch = ((kk << 2) + (lane >> 4)) ^ (lane & 7);
    return *reinterpret_cast<const bf16x8*>(
        &As[buf * ASZ + r * 64 + ch * 8]);
  };
  auto rdB = [&](int buf, int j, int kk) -> bf16x8 {
    int r  = wn * 32 + (j & 1) * 16 + (lane & 15);
    int ch = ((kk << 2) + (lane >> 4)) ^ (lane & 7);
    return *reinterpret_cast<const bf16x8*>(
        &Bs[buf * BSZ + (j >> 1) * 8192 + r * 64 + ch * 8]);
  };

  f32x4 acc[4][4];
#pragma unroll
  for (int i = 0; i < 4; ++i)
#pragma unroll
    for (int j = 0; j < 4; ++j) acc[i][j] = (f32x4){0.f, 0.f, 0.f, 0.f};

  // Prologue: tile0 {A,B0,B1}; vmcnt(2) leaves B1 in flight.
  stageA(0, 0);
  stageB(0, 0, 0);
  stageB(0, 1, 0);
  wait_vmcnt<2>();
  barrier_fence();

  for (int kt = 0; kt < NT; ++kt) {
    const int cur = kt & 1, nxt = cur ^ 1;
    const int k1 = kt + 1 < NT ? kt + 1 : NT - 1;  // clamp keeps counts
    bf16x8 af[4][2], bq0[2][2], bq1[2][2];

    // ---- P0: read A,B0; stage (t+1).{A,B0}; MFMA N-half 0
#pragma unroll
    for (int i = 0; i < 4; ++i)
#pragma unroll
      for (int kk = 0; kk < 2; ++kk) af[i][kk] = rdA(cur, i, kk);
#pragma unroll
    for (int j = 0; j < 2; ++j)
#pragma unroll
      for (int kk = 0; kk < 2; ++kk) bq0[j][kk] = rdB(cur, j, kk);
    stageA(k1, nxt);
    stageB(k1, 0, nxt);
    __builtin_amdgcn_s_setprio(1);
#pragma unroll
    for (int kk = 0; kk < 2; ++kk)
#pragma unroll
      for (int i = 0; i < 4; ++i)
#pragma unroll
        for (int j = 0; j < 2; ++j)
          acc[i][j] = __builtin_amdgcn_mfma_f32_16x16x32_bf16(
              af[i][kk], bq0[j][kk], acc[i][j], 0, 0, 0);
    __builtin_amdgcn_s_setprio(0);
    wait_vmcnt<4>();
    barrier_fence();

    // ---- P1: read B1; stage (t+1).B1; MFMA N-half 1
#pragma unroll
    for (int j = 0; j < 2; ++j)
#pragma unroll
      for (int kk = 0; kk < 2; ++kk) bq1[j][kk] = rdB(cur, 2 + j, kk);
    stageB(k1, 1, nxt);
    __builtin_amdgcn_s_setprio(1);
#pragma unroll
    for (int kk = 0; kk < 2; ++kk)
#pragma unroll
      for (int i = 0; i < 4; ++i)
#pragma unroll
        for (int j = 0; j < 2; ++j)
          acc[i][2 + j] = __builtin_amdgcn_mfma_f32_16x16x32_bf16(
              af[i][kk], bq1[j][kk], acc[i][2 + j], 0, 0, 0);
    __builtin_amdgcn_s_setprio(0);
    wait_vmcnt<2>();
    barrier_fence();
  }

  // Epilogue. C/D layout (m89): col = lane&15, row = (lane>>4)*4 + reg
#pragma unroll
  for (int i = 0; i < 4; ++i) {
    int rb = bm + (i >> 1) * 64 + wm * 32 + (i & 1) * 16 + ((lane >> 4) << 2);
#pragma unroll
    for (int rr = 0; rr < 4; ++rr) {
      const int grow = rb + rr;
      if constexpr (EPI == 0) {
        const float g = mg[grow * NLEAF + (bn >> 8)];  // BN=256 = one leaf
#pragma unroll
        for (int j = 0; j < 4; ++j) {
          const int gcol =
              bn + (j >> 1) * 128 + wn * 32 + (j & 1) * 16 + (lane & 15);
          float v = acc[i][j][rr] + bias[gcol];
          v = v > 0.f ? v : 0.f;
          outB[(size_t)grow * KEXT + gcol] = (bf16)(v * g);
        }
      } else {
#pragma unroll
        for (int j = 0; j < 4; ++j) {
          const int gcol =
              bn + (j >> 1) * 128 + wn * 32 + (j & 1) * 16 + (lane & 15);
          outF[(size_t)grow * OUTF + gcol] = acc[i][j][rr];
        }
      }
    }
  }
}

// ---------------------------------------------------------------------------
extern "C" void kernel_launch(void* const* d_in, const int* in_sizes, int n_in,
                              void* d_out, int out_size, void* d_ws,
                              size_t ws_size, hipStream_t stream) {
  const float* x   = (const float*)d_in[0];  // [8192][1024]
  const float* nw  = (const float*)d_in[1];  // [15][1024]
  const float* nb  = (const float*)d_in[2];  // [15]
  const float* w1s = (const float*)d_in[3];  // [16][1024][256]
  const float* b1s = (const float*)d_in[4];  // [16][256] -> flat [4096]
  const float* w2s = (const float*)d_in[5];  // [16][256][1024]
  const float* b2s = (const float*)d_in[6];  // [16][1024]
  float* out = (float*)d_out;                // [8192][1024]

  char* ws = (char*)d_ws;
  bf16*  Xbf  = (bf16*)(ws);                  // 16,777,216 B
  bf16*  W1T  = (bf16*)(ws + 16777216);       //  8,388,608 B  [4096][1024]
  bf16*  W2T  = (bf16*)(ws + 25165824);       //  8,519,680 B  [1024][4160]
  float* mg   = (float*)(ws + 33685504);      //    524,288 B  [8192][16]
  bf16*  Aact = (bf16*)(ws + 34209792);       // 68,157,440 B  [8192][4160]

  // One merged prep+gating launch: 8448 prep blocks + 2048 gating blocks
  prep_gating_kernel<<<dim3(10496), 256, 0, stream>>>(
      w1s, w2s, b2s, (const float4*)x, (const float4*)nw, nb, W1T, W2T, mg,
      Aact, (bf16x4*)Xbf);

  // GEMM1: Aact[:, :4096] = relu(Xbf @ W1T^T + b1) * mixture
  // 128x256 tile: grid 64*16 = 1024 blocks
  gemm_kernel<0, INF, 16><<<dim3(1024), 512, 0, stream>>>(
      Xbf, W1T, b1s, mg, Aact, nullptr);
  // GEMM2: out = Aact @ W2T^T (K = 4160 includes mixture @ B2 term)
  // 128x256 tile: grid 64*4 = 256 blocks
  gemm_kernel<1, KEXT, 4><<<dim3(256), 512, 0, stream>>>(
      Aact, W2T, nullptr, nullptr, nullptr, out);
}